// Round 13
// baseline (103.403 us; speedup 1.0000x reference)
//
#include <hip/hip_runtime.h>
#include <hip/hip_bf16.h>
#include <math.h>

// ---------------------------------------------------------------------------
// DeepseekMoE: T=16384 tokens, D=128, E=64 experts top-6, M=80, shared MS=160.
// R13 (on R12's global_load_lds win):
//  - GEMM2 loop swap: preload hl b-frags (bfr[2][3], 6 reads) and stream ad;
//    GEMM2 LDS reads 72 -> 30 per wave.
//  - Shared chunks = 128 tokens x 2 halves (staging halved, 128 chunks),
//    scheduled FIRST (LPT).
// ---------------------------------------------------------------------------

typedef unsigned short ushort_t;
typedef __attribute__((ext_vector_type(8))) short bf16x8;   // 8 bf16 = 4 VGPR
typedef __attribute__((ext_vector_type(4))) float f32x4;

#define EALL  66

// ---- fast-mode workspace byte offsets ----
#define OFF_TOPKI 16384
#define OFF_WORK  409600             // int [1088] worklist
#define OFF_TOPKW 802816
#define OFF_PERM  1196032
#define OFF_PERMW 1589248
#define OFF_POS2  1982464
#define OFF_YPERM 2375680            // bf16 [98304][128] = 25165824
#define OFF_YSH   27541504           // bf16 [16384][128] = 4194304
#define OFF_WGT   31735808           // bf16 [66][80][128] = 1351680
#define OFF_WUT   33087488
#define OFF_WDP   34439168           // bf16 [66][128][96] = 1622016 (zero-padded)
#define OFF_XB    36061184           // bf16 [16384][128] = 4194304
#define OFF_HIST  40255488
#define OFF_BOFF  40321024
#define NEED_FAST 40386560
// ---- fallback (compact) offsets: ybuf replaces yperm/ysh ----
#define FOFF_YBUF 2375680            // float[16384*128] = 8388608
#define FOFF_WGT  10764288
#define FOFF_WUT  12115968
#define FOFF_WDP  13467648
#define FOFF_XB   15089664
#define FOFF_HIST 19283968
#define FOFF_BOFF 19349504
// int ws indices: Wi[0..63]=cnt, Wi[64..127]=excl, Wi[128]=total, Wi[193]=nwork.

__device__ __forceinline__ float bf2f(ushort_t u) {
    unsigned int x = ((unsigned int)u) << 16;
    float f; __builtin_memcpy(&f, &x, 4); return f;
}
__device__ __forceinline__ ushort_t f2bf(float f) {
    unsigned int x; __builtin_memcpy(&x, &f, 4);
    unsigned int r = (x + 0x7fffu + ((x >> 16) & 1u)) >> 16;   // RNE
    return (ushort_t)r;
}
__device__ __forceinline__ float ldin(const void* p, int i, int f32m) {
    return f32m ? ((const float*)p)[i] : bf2f(((const ushort_t*)p)[i]);
}
__device__ __forceinline__ int detect_f32m(const ushort_t* gw) {
    int lane = threadIdx.x & 63;
    int cnt = 0;
    #pragma unroll
    for (int j = 0; j < 4; ++j) {
        ushort_t u = gw[lane * 4 + j];
        if (((u >> 7) & 0xFF) >= 0x7C) cnt++;
    }
    #pragma unroll
    for (int off = 32; off; off >>= 1) cnt += __shfl_xor(cnt, off);
    return (cnt >= 8) ? 1 : 0;
}
// async 16B/lane global -> LDS (dest = uniform base + lane*16)
__device__ __forceinline__ void gl16(void* l, const void* g) {
    __builtin_amdgcn_global_load_lds(
        (const __attribute__((address_space(1))) void*)g,
        (__attribute__((address_space(3))) void*)l, 16, 0, 0);
}

// ---------------------------------------------------------------------------
// Fused prep+gate. Blocks [0, 3*EALL): weight transpose (1024 thr).
// Blocks [3*EALL, 3*EALL+256): gating (16 waves x 4 tokens).
// ---------------------------------------------------------------------------
__global__ __launch_bounds__(1024) void k_pg(const void* x, const void* gw,
        const void* wg, const void* wu, const void* wd,
        const void* swg, const void* swu, const void* swd,
        ushort_t* wgT, ushort_t* wuT, ushort_t* wdP,
        ushort_t* xB, int* topk_i, float* topk_w, int* histPart) {
    __shared__ __align__(16) char smem[41984];
    int tid = threadIdx.x, bid = blockIdx.x;
    int f32m = detect_f32m((const ushort_t*)gw);

    if (bid < 3 * EALL) {
        float* lds = (float*)smem;
        int mat = bid / EALL, e = bid % EALL;
        if (mat < 2) {
            const void* src  = (mat == 0) ? wg  : wu;
            const void* ssrc = (mat == 0) ? swg : swu;
            for (int i = tid; i < 10240; i += 1024) {
                int d = i / 80, m = i % 80;
                float v = (e < 64) ? ldin(src, e * 10240 + i, f32m)
                                   : ldin(ssrc, d * 160 + (e - 64) * 80 + m, f32m);
                lds[d * 81 + m] = v;
            }
            __syncthreads();
            ushort_t* dst = ((mat == 0) ? wgT : wuT) + e * 10240;
            for (int o = tid; o < 10240; o += 1024) {
                int m = o >> 7, d = o & 127;
                dst[o] = f2bf(lds[d * 81 + m]);
            }
        } else {
            for (int i = tid; i < 10240; i += 1024) {
                float v = (e < 64) ? ldin(wd, e * 10240 + i, f32m)
                                   : ldin(swd, (e - 64) * 10240 + i, f32m);
                int m = i >> 7, d = i & 127;
                lds[m * 129 + d] = v;
            }
            __syncthreads();
            ushort_t* dst = wdP + e * 12288;
            for (int o = tid; o < 12288; o += 1024) {
                int d = o / 96, m = o % 96;
                dst[o] = (m < 80) ? f2bf(lds[m * 129 + d]) : (ushort_t)0;
            }
        }
        return;
    }

    // -------- gate --------
    float* gwl  = (float*)smem;                 // 64 x 130 f32
    float (*xl)[128] = (float(*)[128])(smem + 33280);
    int*   histL = (int*)(smem + 41472);
    int b = bid - 3 * EALL;
    for (int i = tid; i < 8192; i += 1024)
        gwl[(i >> 7) * 130 + (i & 127)] = ldin(gw, i, f32m);
    if (tid < 64) histL[tid] = 0;
    __syncthreads();
    int wv = tid >> 6, lane = tid & 63;
    for (int q = 0; q < 4; ++q) {
        int t = b * 64 + wv * 4 + q;
        float xv0, xv1;
        if (f32m) {
            float2 v = ((const float2*)((const float*)x + t * 128))[lane];
            xv0 = v.x; xv1 = v.y;
        } else {
            unsigned int pr = *(const unsigned int*)((const ushort_t*)x + t * 128 + lane * 2);
            xv0 = bf2f((ushort_t)(pr & 0xffffu));
            xv1 = bf2f((ushort_t)(pr >> 16));
        }
        float2 xw; xw.x = xv0; xw.y = xv1;
        *(float2*)&xl[wv][lane * 2] = xw;
        unsigned int packed = (unsigned int)f2bf(xv0) | ((unsigned int)f2bf(xv1) << 16);
        *(unsigned int*)(xB + t * 128 + lane * 2) = packed;
        float acc = 0.f;
        #pragma unroll
        for (int d2 = 0; d2 < 64; ++d2) {
            float2 xv = *(const float2*)&xl[wv][d2 * 2];
            float2 gv = *(const float2*)&gwl[lane * 130 + d2 * 2];
            acc = fmaf(xv.x, gv.x, acc);
            acc = fmaf(xv.y, gv.y, acc);
        }
        float mx = acc;
        #pragma unroll
        for (int off = 32; off; off >>= 1) mx = fmaxf(mx, __shfl_xor(mx, off));
        float p = expf(acc - mx);
        float sm = p;
        #pragma unroll
        for (int off = 32; off; off >>= 1) sm += __shfl_xor(sm, off);
        float sc = p / sm;
        float cur = sc;
        float wk6[6]; int ik[6];
        #pragma unroll
        for (int k = 0; k < 6; ++k) {
            float bv = cur; int bi = lane;
            #pragma unroll
            for (int off = 1; off < 64; off <<= 1) {
                float ov = __shfl_xor(bv, off); int oi = __shfl_xor(bi, off);
                if (ov > bv || (ov == bv && oi < bi)) { bv = ov; bi = oi; }
            }
            wk6[k] = bv; ik[k] = bi;
            if (lane == bi) cur = -INFINITY;
        }
        if (lane == 0) {
            float den = wk6[0] + wk6[1] + wk6[2] + wk6[3] + wk6[4] + wk6[5] + 1e-20f;
            #pragma unroll
            for (int k = 0; k < 6; ++k) {
                topk_i[t * 6 + k] = ik[k];
                topk_w[t * 6 + k] = wk6[k] / den;
                atomicAdd(&histL[ik[k]], 1);
            }
        }
    }
    __syncthreads();
    if (tid < 64) histPart[tid * 256 + b] = histL[tid];
}

// ---------------------------------------------------------------------------
// Scan (1 block): per-expert scan, bases, worklist. 128 shared 128-token
// chunks FIRST (LPT: 2x work each), routed 128-token chunks after.
// ---------------------------------------------------------------------------
__global__ __launch_bounds__(256) void k_scan(int* Wi, const int* histPart,
        int* boffG, int* wk) {
    __shared__ int hl[16384];
    __shared__ int cntL[64], exclL[64], chxL[65];
    int tid = threadIdx.x, lane = tid & 63, wv = tid >> 6;
    for (int j = tid; j < 16384; j += 256) hl[j] = histPart[j];
    __syncthreads();
    for (int ei = 0; ei < 16; ++ei) {
        int e = wv * 16 + ei;
        int carry = 0;
        for (int r = 0; r < 4; ++r) {
            int v = hl[e * 256 + r * 64 + lane];
            int incl = v;
            #pragma unroll
            for (int off = 1; off < 64; off <<= 1) {
                int ts = __shfl_up(incl, off);
                if (lane >= off) incl += ts;
            }
            hl[e * 256 + r * 64 + lane] = carry + incl - v;
            carry += __shfl(incl, 63);
        }
        if (lane == 0) cntL[e] = carry;
    }
    __syncthreads();
    if (tid == 0) {
        int s = 0, cs = 0;
        for (int e = 0; e < 64; ++e) {
            exclL[e] = s; s += cntL[e];
            chxL[e] = cs; cs += (cntL[e] + 127) >> 7;
        }
        chxL[64] = cs;
        Wi[128] = s;
        Wi[193] = cs + 128;   // nwork (+128 shared 128-token chunks)
    }
    __syncthreads();
    if (tid < 64) { Wi[tid] = cntL[tid]; Wi[64 + tid] = exclL[tid]; }
    for (int j = tid; j < 16384; j += 256) boffG[j] = hl[j] + exclL[j >> 8];
    if (tid < 128) wk[tid] = (64 << 16) | tid;   // shared chunks first
    if (tid < 64) {
        int e = tid, nc = (cntL[e] + 127) >> 7, bb = chxL[e];
        for (int c = 0; c < nc; ++c) wk[128 + bb + c] = (e << 16) | c;
    }
}

// ---------------------------------------------------------------------------
// Scatter: LDS counters seeded from boffG; records pos2 for the gather.
// ---------------------------------------------------------------------------
__global__ __launch_bounds__(256) void k_scatter(const int* topk_i, const float* topk_w,
        const int* boffG, int* perm, float* permw, int* pos2) {
    __shared__ int lcur[64];
    int tid = threadIdx.x, b = blockIdx.x;
    if (tid < 64) lcur[tid] = boffG[tid * 256 + b];
    __syncthreads();
    for (int i = tid; i < 384; i += 256) {
        int g = b * 384 + i;
        int e = topk_i[g];
        float w = topk_w[g];
        int p = atomicAdd(&lcur[e], 1);
        perm[p]  = b * 64 + i / 6;
        permw[p] = w;
        pos2[g]  = p;
    }
}

// ---------------------------------------------------------------------------
// Expert MLP v10: global_load_lds staging (pre-swizzled src, linear dest);
// GEMM2 preloads hl b-frags (6 reads) and streams ad (24 reads).
// Routed: 128-token chunk, wave owns 32 rows, nsub=1. Shared (e==64):
// 128-token chunk, nsub=2, acc accumulated across halves. LDS 72KB.
// Swizzle: byte = row*256 + (chunk16 ^ (row&7))*16.
// ---------------------------------------------------------------------------
template<int FAST>
__global__ __launch_bounds__(256) void k_expert(const ushort_t* x, const ushort_t* wgT,
        const ushort_t* wuT, const ushort_t* wdP, const int* Wi, const int* wk,
        const int* perm, const float* permw, ushort_t* yperm, ushort_t* ysh, float* ybuf) {
    __shared__ __align__(16) char hl[32768];
    __shared__ __align__(16) char bufA[20480];
    __shared__ __align__(16) char bufB[20480];

    if (blockIdx.x >= Wi[193]) return;
    int entry = wk[blockIdx.x];
    int e = entry >> 16, c = entry & 0xffff;
    int tid = threadIdx.x, lid = tid & 63, wv = tid >> 6;
    int kg  = (lid >> 4) * 16;
    int kq8 = (lid >> 4) * 8;

    int nrows = 128, base = 0;
    int nsub = 1;
    if (e < 64) {
        int n = Wi[e]; base = Wi[64 + e];
        nrows = n - c * 128; if (nrows > 128) nrows = 128;
    } else {
        nsub = 2;
    }

    // A fragments (tokens) in registers — persistent across subs
    bf16x8 a[2][4];
    #pragma unroll
    for (int tr = 0; tr < 2; ++tr) {
        int arow = wv * 32 + tr * 16 + (lid & 15);
        int t;
        if (e < 64) {
            int r = (arow < nrows) ? arow : (nrows - 1);
            t = perm[base + c * 128 + r];
        } else {
            t = c * 128 + arow;
        }
        #pragma unroll
        for (int k = 0; k < 4; ++k)
            a[tr][k] = *(const bf16x8*)(x + t * 128 + k * 32 + kq8);
    }

    f32x4 acc[8][2];
    #pragma unroll
    for (int dt = 0; dt < 8; ++dt) {
        acc[dt][0] = (f32x4){0.f, 0.f, 0.f, 0.f};
        acc[dt][1] = (f32x4){0.f, 0.f, 0.f, 0.f};
    }

    for (int sub = 0; sub < nsub; ++sub) {
        int ee = (e < 64) ? e : (64 + sub);

        // stage wg -> bufA, wu -> bufB (pre-swizzled source, linear dest)
        {
            const ushort_t* gS = wgT + ee * 10240;
            const ushort_t* uS = wuT + ee * 10240;
            #pragma unroll
            for (int i = 0; i < 5; ++i) {
                int s = wv * 320 + i * 64 + lid;
                int row = s >> 4, sc = (s & 15) ^ (row & 7);
                gl16(bufA + wv * 5120 + i * 1024, gS + row * 128 + sc * 8);
                gl16(bufB + wv * 5120 + i * 1024, uS + row * 128 + sc * 8);
            }
        }
        __syncthreads();

        // GEMM1: B from LDS, h -> own hl rows
        #pragma unroll
        for (int mi = 0; mi < 5; ++mi) {
            int brow = mi * 16 + (lid & 15);
            int bro = brow * 256, bsw = (brow & 7) << 4;
            f32x4 ag[2], au[2];
            #pragma unroll
            for (int tr = 0; tr < 2; ++tr) {
                ag[tr] = (f32x4){0.f, 0.f, 0.f, 0.f};
                au[tr] = (f32x4){0.f, 0.f, 0.f, 0.f};
            }
            #pragma unroll
            for (int k = 0; k < 4; ++k) {
                int bo = bro + (((k * 64) + kg) ^ bsw);
                bf16x8 bg = *(const bf16x8*)(bufA + bo);
                bf16x8 bu = *(const bf16x8*)(bufB + bo);
                #pragma unroll
                for (int tr = 0; tr < 2; ++tr) {
                    ag[tr] = __builtin_amdgcn_mfma_f32_16x16x32_bf16(a[tr][k], bg, ag[tr], 0, 0, 0);
                    au[tr] = __builtin_amdgcn_mfma_f32_16x16x32_bf16(a[tr][k], bu, au[tr], 0, 0, 0);
                }
            }
            #pragma unroll
            for (int tr = 0; tr < 2; ++tr) {
                #pragma unroll
                for (int rg = 0; rg < 4; ++rg) {
                    float g = ag[tr][rg], uu2 = au[tr][rg];
                    float h = (g / (1.f + __expf(-g))) * uu2;
                    int row = wv * 32 + tr * 16 + (lid >> 4) * 4 + rg;
                    int cb = (mi * 16 + (lid & 15)) * 2;
                    *(ushort_t*)(hl + row * 256 + (cb ^ ((row & 7) << 4))) = f2bf(h);
                }
            }
        }
        if (sub == 0) {   // zero-pad own rows, K cols 80..95 (once)
            int r = wv * 32 + (lid >> 1), ch = 10 + (lid & 1);
            uint4 z = {0u, 0u, 0u, 0u};
            *(uint4*)(hl + r * 256 + ((ch * 16) ^ ((r & 7) << 4))) = z;
        }
        __syncthreads();   // all waves done reading bufA/bufB

        // stage wd rows 0..63 -> bufA, rows 64..127 -> bufB
        {
            const ushort_t* dS = wdP + ee * 12288;
            #pragma unroll
            for (int i = 0; i < 4; ++i) {
                int s = wv * 256 + i * 64 + lid;
                int r = s >> 4, sc = (s & 15) ^ (r & 7);
                int off = (sc < 12) ? sc * 8 : 0;
                gl16(bufA + wv * 4096 + i * 1024, dS + r * 96 + off);
                gl16(bufB + wv * 4096 + i * 1024, dS + (64 + r) * 96 + off);
            }
        }
        __syncthreads();

        // GEMM2: preload b-frags (own hl rows, 6 reads), stream ad (3/dt)
        bf16x8 bfr[2][3];
        #pragma unroll
        for (int tf = 0; tf < 2; ++tf) {
            int brow = wv * 32 + tf * 16 + (lid & 15);
            #pragma unroll
            for (int k = 0; k < 3; ++k)
                bfr[tf][k] = *(const bf16x8*)(hl + brow * 256 + (((k * 64) + kg) ^ ((brow & 7) << 4)));
        }
        #pragma unroll
        for (int dt = 0; dt < 8; ++dt) {
            int r = (dt & 3) * 16 + (lid & 15);
            const char* wb = (dt < 4) ? bufA : bufB;
            bf16x8 ad[3];
            #pragma unroll
            for (int k = 0; k < 3; ++k)
                ad[k] = *(const bf16x8*)(wb + r * 256 + (((k * 64) + kg) ^ ((r & 7) << 4)));
            #pragma unroll
            for (int tf = 0; tf < 2; ++tf) {
                f32x4 cc = acc[dt][tf];
                #pragma unroll
                for (int k = 0; k < 3; ++k)
                    cc = __builtin_amdgcn_mfma_f32_16x16x32_bf16(ad[k], bfr[tf][k], cc, 0, 0, 0);
                acc[dt][tf] = cc;
            }
        }
        if (sub + 1 < nsub) __syncthreads();   // before restaging bufA/bufB
    }

    // epilogue: scale -> swizzled LDS stage (own rows) -> coalesced stores
    #pragma unroll
    for (int tf = 0; tf < 2; ++tf) {
        int rloc = wv * 32 + tf * 16 + (lid & 15);
        int rc = (rloc < nrows) ? rloc : (nrows - 1);
        float w;
        if (e < 64) w = FAST ? permw[base + c * 128 + rc] : 0.f;
        else        w = 1.0f;
        #pragma unroll
        for (int dt = 0; dt < 8; ++dt) {
            if (FAST) {
                int cb = (dt * 16 + (lid >> 4) * 4) * 2;
                ushort_t o[4];
                #pragma unroll
                for (int rg = 0; rg < 4; ++rg) o[rg] = f2bf(acc[dt][tf][rg] * w);
                *(uint2*)(hl + rloc * 256 + (cb ^ ((rloc & 7) << 4))) = *(const uint2*)o;
            } else {
                if (rloc < nrows) {
                    int t; float w2;
                    if (e < 64) { t = perm[base + c * 128 + rloc]; w2 = permw[base + c * 128 + rloc]; }
                    else        { t = c * 128 + rloc; w2 = 1.0f; }
                    int d0 = dt * 16 + (lid >> 4) * 4;
                    #pragma unroll
                    for (int rg = 0; rg < 4; ++rg)
                        atomicAdd(&ybuf[t * 128 + d0 + rg], acc[dt][tf][rg] * w2);
                }
            }
        }
    }
    if (FAST) {
        #pragma unroll
        for (int ps = 0; ps < 8; ++ps) {
            int row = wv * 32 + ps * 4 + (lid >> 4);
            int cb = (lid & 15) * 16;
            uint4 v = *(const uint4*)(hl + row * 256 + (cb ^ ((row & 7) << 4)));
            if (row < nrows) {
                ushort_t* dst = (e < 64)
                    ? (yperm + (size_t)(base + c * 128 + row) * 128)
                    : (ysh   + (size_t)(c * 128 + row) * 128);
                *(uint4*)(dst + (lid & 15) * 8) = v;
            }
        }
    }
}

// ---------------------------------------------------------------------------
// Final gather: out[t] = sum_k yperm[pos2[t*6+k]] + ysh[t].
// ---------------------------------------------------------------------------
__global__ __launch_bounds__(256) void k_final_gather(const ushort_t* yperm,
        const ushort_t* ysh, const int* pos2, void* out, const ushort_t* gwDet) {
    int idx = blockIdx.x * 256 + threadIdx.x;
    int t = idx >> 4, cg = (idx & 15) * 8;
    int f32m = detect_f32m(gwDet);
    float acc[8];
    {
        uint4 v = *(const uint4*)(ysh + (size_t)t * 128 + cg);
        const ushort_t* u = (const ushort_t*)&v;
        #pragma unroll
        for (int j = 0; j < 8; ++j) acc[j] = bf2f(u[j]);
    }
    const int* pp = pos2 + t * 6;
    #pragma unroll
    for (int k = 0; k < 6; ++k) {
        int p = pp[k];
        uint4 v = *(const uint4*)(yperm + (size_t)p * 128 + cg);
        const ushort_t* u = (const ushort_t*)&v;
        #pragma unroll
        for (int j = 0; j < 8; ++j) acc[j] += bf2f(u[j]);
    }
    if (f32m) {
        float4 o0 = {acc[0], acc[1], acc[2], acc[3]};
        float4 o1 = {acc[4], acc[5], acc[6], acc[7]};
        float* op = (float*)out + (size_t)t * 128 + cg;
        *(float4*)op = o0; *(float4*)(op + 4) = o1;
    } else {
        ushort_t o[8];
        #pragma unroll
        for (int j = 0; j < 8; ++j) o[j] = f2bf(acc[j]);
        *(uint4*)((ushort_t*)out + (size_t)t * 128 + cg) = *(const uint4*)o;
    }
}

// fallback: read fp32 ybuf
__global__ __launch_bounds__(256) void k_final_ybuf(const float* ybuf, void* out,
        const ushort_t* gwDet) {
    int i = blockIdx.x * 256 + threadIdx.x;
    int f32m = detect_f32m(gwDet);
    float4 v = ((const float4*)ybuf)[i];
    if (f32m) {
        ((float4*)out)[i] = v;
    } else {
        ushort4 o;
        o.x = f2bf(v.x); o.y = f2bf(v.y); o.z = f2bf(v.z); o.w = f2bf(v.w);
        ((ushort4*)out)[i] = o;
    }
}

// ---------------------------------------------------------------------------
extern "C" void kernel_launch(void* const* d_in, const int* in_sizes, int n_in,
                              void* d_out, int out_size, void* d_ws, size_t ws_size,
                              hipStream_t stream) {
    (void)in_sizes; (void)n_in; (void)out_size;
    const void* x   = d_in[0];
    const void* gw  = d_in[1];
    const void* wg  = d_in[2];
    const void* wu  = d_in[3];
    const void* wd  = d_in[4];
    const void* swg = d_in[5];
    const void* swu = d_in[6];
    const void* swd = d_in[7];

    char* ws = (char*)d_ws;
    int fast = (ws_size >= (size_t)NEED_FAST) ? 1 : 0;

    int*      Wi     = (int*)d_ws;
    int*      topk_i = (int*)(ws + OFF_TOPKI);
    int*      wklist = (int*)(ws + OFF_WORK);
    float*    topk_w = (float*)(ws + OFF_TOPKW);
    int*      perm   = (int*)(ws + OFF_PERM);
    float*    permw  = (float*)(ws + OFF_PERMW);
    int*      pos2   = (int*)(ws + OFF_POS2);

    ushort_t* yperm = (ushort_t*)(ws + OFF_YPERM);
    ushort_t* ysh   = (ushort_t*)(ws + OFF_YSH);
    float*    ybuf  = (float*)(ws + FOFF_YBUF);
    ushort_t* wgT   = (ushort_t*)(ws + (fast ? OFF_WGT  : FOFF_WGT));
    ushort_t* wuT   = (ushort_t*)(ws + (fast ? OFF_WUT  : FOFF_WUT));
    ushort_t* wdP   = (ushort_t*)(ws + (fast ? OFF_WDP  : FOFF_WDP));
    ushort_t* xB    = (ushort_t*)(ws + (fast ? OFF_XB   : FOFF_XB));
    int*      histP = (int*)(ws + (fast ? OFF_HIST : FOFF_HIST));
    int*      boffG = (int*)(ws + (fast ? OFF_BOFF : FOFF_BOFF));

    if (!fast) hipMemsetAsync(ybuf, 0, 16384 * 128 * 4, stream);

    k_pg<<<3 * EALL + 256, 1024, 0, stream>>>(x, gw, wg, wu, wd, swg, swu, swd,
                                              wgT, wuT, wdP, xB, topk_i, topk_w, histP);
    k_scan<<<1, 256, 0, stream>>>(Wi, histP, boffG, wklist);
    k_scatter<<<256, 256, 0, stream>>>(topk_i, topk_w, boffG, perm, permw, pos2);
    if (fast) {
        k_expert<1><<<1088, 256, 0, stream>>>(xB, wgT, wuT, wdP, Wi, wklist, perm, permw, yperm, ysh, ybuf);
        k_final_gather<<<1024, 256, 0, stream>>>(yperm, ysh, pos2, d_out, (const ushort_t*)gw);
    } else {
        k_expert<0><<<1088, 256, 0, stream>>>(xB, wgT, wuT, wdP, Wi, wklist, perm, permw, yperm, ysh, ybuf);
        k_final_ybuf<<<2048, 256, 0, stream>>>(ybuf, d_out, (const ushort_t*)gw);
    }
}

// Round 14
// 92.652 us; speedup vs baseline: 1.1160x; 1.1160x over previous
//
#include <hip/hip_runtime.h>
#include <hip/hip_bf16.h>
#include <math.h>

// ---------------------------------------------------------------------------
// DeepseekMoE: T=16384 tokens, D=128, E=64 experts top-6, M=80, shared MS=160.
// R14 = R12 exact (92.8us: global_load_lds staging, pre-swizzled src, shared
//       64-tok chunks x2 subs first) + GEMM2 loop swap in ROUTED path only
//       (preload bfr[2][3] from own hl rows, stream ad: LDS reads 72->30).
//       R13's unified-path/128-tok-shared experiment reverted (regressed).
// ---------------------------------------------------------------------------

typedef unsigned short ushort_t;
typedef __attribute__((ext_vector_type(8))) short bf16x8;   // 8 bf16 = 4 VGPR
typedef __attribute__((ext_vector_type(4))) float f32x4;

#define EALL  66

// ---- fast-mode workspace byte offsets ----
#define OFF_TOPKI 16384
#define OFF_WORK  409600             // int [1088] worklist
#define OFF_TOPKW 802816
#define OFF_PERM  1196032
#define OFF_PERMW 1589248
#define OFF_POS2  1982464
#define OFF_YPERM 2375680            // bf16 [98304][128] = 25165824
#define OFF_YSH   27541504           // bf16 [16384][128] = 4194304
#define OFF_WGT   31735808           // bf16 [66][80][128] = 1351680
#define OFF_WUT   33087488
#define OFF_WDP   34439168           // bf16 [66][128][96] = 1622016 (zero-padded)
#define OFF_XB    36061184           // bf16 [16384][128] = 4194304
#define OFF_HIST  40255488
#define OFF_BOFF  40321024
#define NEED_FAST 40386560
// ---- fallback (compact) offsets: ybuf replaces yperm/ysh ----
#define FOFF_YBUF 2375680            // float[16384*128] = 8388608
#define FOFF_WGT  10764288
#define FOFF_WUT  12115968
#define FOFF_WDP  13467648
#define FOFF_XB   15089664
#define FOFF_HIST 19283968
#define FOFF_BOFF 19349504
// int ws indices: Wi[0..63]=cnt, Wi[64..127]=excl, Wi[128]=total, Wi[193]=nwork.

__device__ __forceinline__ float bf2f(ushort_t u) {
    unsigned int x = ((unsigned int)u) << 16;
    float f; __builtin_memcpy(&f, &x, 4); return f;
}
__device__ __forceinline__ ushort_t f2bf(float f) {
    unsigned int x; __builtin_memcpy(&x, &f, 4);
    unsigned int r = (x + 0x7fffu + ((x >> 16) & 1u)) >> 16;   // RNE
    return (ushort_t)r;
}
__device__ __forceinline__ float ldin(const void* p, int i, int f32m) {
    return f32m ? ((const float*)p)[i] : bf2f(((const ushort_t*)p)[i]);
}
__device__ __forceinline__ int detect_f32m(const ushort_t* gw) {
    int lane = threadIdx.x & 63;
    int cnt = 0;
    #pragma unroll
    for (int j = 0; j < 4; ++j) {
        ushort_t u = gw[lane * 4 + j];
        if (((u >> 7) & 0xFF) >= 0x7C) cnt++;
    }
    #pragma unroll
    for (int off = 32; off; off >>= 1) cnt += __shfl_xor(cnt, off);
    return (cnt >= 8) ? 1 : 0;
}
// async 16B/lane global -> LDS (dest = uniform base + lane*16)
__device__ __forceinline__ void gl16(void* l, const void* g) {
    __builtin_amdgcn_global_load_lds(
        (const __attribute__((address_space(1))) void*)g,
        (__attribute__((address_space(3))) void*)l, 16, 0, 0);
}

// ---------------------------------------------------------------------------
// Fused prep+gate. Blocks [0, 3*EALL): weight transpose (1024 thr).
// Blocks [3*EALL, 3*EALL+256): gating (16 waves x 4 tokens).
// ---------------------------------------------------------------------------
__global__ __launch_bounds__(1024) void k_pg(const void* x, const void* gw,
        const void* wg, const void* wu, const void* wd,
        const void* swg, const void* swu, const void* swd,
        ushort_t* wgT, ushort_t* wuT, ushort_t* wdP,
        ushort_t* xB, int* topk_i, float* topk_w, int* histPart) {
    __shared__ __align__(16) char smem[41984];
    int tid = threadIdx.x, bid = blockIdx.x;
    int f32m = detect_f32m((const ushort_t*)gw);

    if (bid < 3 * EALL) {
        float* lds = (float*)smem;
        int mat = bid / EALL, e = bid % EALL;
        if (mat < 2) {
            const void* src  = (mat == 0) ? wg  : wu;
            const void* ssrc = (mat == 0) ? swg : swu;
            for (int i = tid; i < 10240; i += 1024) {
                int d = i / 80, m = i % 80;
                float v = (e < 64) ? ldin(src, e * 10240 + i, f32m)
                                   : ldin(ssrc, d * 160 + (e - 64) * 80 + m, f32m);
                lds[d * 81 + m] = v;
            }
            __syncthreads();
            ushort_t* dst = ((mat == 0) ? wgT : wuT) + e * 10240;
            for (int o = tid; o < 10240; o += 1024) {
                int m = o >> 7, d = o & 127;
                dst[o] = f2bf(lds[d * 81 + m]);
            }
        } else {
            for (int i = tid; i < 10240; i += 1024) {
                float v = (e < 64) ? ldin(wd, e * 10240 + i, f32m)
                                   : ldin(swd, (e - 64) * 10240 + i, f32m);
                int m = i >> 7, d = i & 127;
                lds[m * 129 + d] = v;
            }
            __syncthreads();
            ushort_t* dst = wdP + e * 12288;
            for (int o = tid; o < 12288; o += 1024) {
                int d = o / 96, m = o % 96;
                dst[o] = (m < 80) ? f2bf(lds[m * 129 + d]) : (ushort_t)0;
            }
        }
        return;
    }

    // -------- gate --------
    float* gwl  = (float*)smem;                 // 64 x 130 f32
    float (*xl)[128] = (float(*)[128])(smem + 33280);
    int*   histL = (int*)(smem + 41472);
    int b = bid - 3 * EALL;
    for (int i = tid; i < 8192; i += 1024)
        gwl[(i >> 7) * 130 + (i & 127)] = ldin(gw, i, f32m);
    if (tid < 64) histL[tid] = 0;
    __syncthreads();
    int wv = tid >> 6, lane = tid & 63;
    for (int q = 0; q < 4; ++q) {
        int t = b * 64 + wv * 4 + q;
        float xv0, xv1;
        if (f32m) {
            float2 v = ((const float2*)((const float*)x + t * 128))[lane];
            xv0 = v.x; xv1 = v.y;
        } else {
            unsigned int pr = *(const unsigned int*)((const ushort_t*)x + t * 128 + lane * 2);
            xv0 = bf2f((ushort_t)(pr & 0xffffu));
            xv1 = bf2f((ushort_t)(pr >> 16));
        }
        float2 xw; xw.x = xv0; xw.y = xv1;
        *(float2*)&xl[wv][lane * 2] = xw;
        unsigned int packed = (unsigned int)f2bf(xv0) | ((unsigned int)f2bf(xv1) << 16);
        *(unsigned int*)(xB + t * 128 + lane * 2) = packed;
        float acc = 0.f;
        #pragma unroll
        for (int d2 = 0; d2 < 64; ++d2) {
            float2 xv = *(const float2*)&xl[wv][d2 * 2];
            float2 gv = *(const float2*)&gwl[lane * 130 + d2 * 2];
            acc = fmaf(xv.x, gv.x, acc);
            acc = fmaf(xv.y, gv.y, acc);
        }
        float mx = acc;
        #pragma unroll
        for (int off = 32; off; off >>= 1) mx = fmaxf(mx, __shfl_xor(mx, off));
        float p = expf(acc - mx);
        float sm = p;
        #pragma unroll
        for (int off = 32; off; off >>= 1) sm += __shfl_xor(sm, off);
        float sc = p / sm;
        float cur = sc;
        float wk6[6]; int ik[6];
        #pragma unroll
        for (int k = 0; k < 6; ++k) {
            float bv = cur; int bi = lane;
            #pragma unroll
            for (int off = 1; off < 64; off <<= 1) {
                float ov = __shfl_xor(bv, off); int oi = __shfl_xor(bi, off);
                if (ov > bv || (ov == bv && oi < bi)) { bv = ov; bi = oi; }
            }
            wk6[k] = bv; ik[k] = bi;
            if (lane == bi) cur = -INFINITY;
        }
        if (lane == 0) {
            float den = wk6[0] + wk6[1] + wk6[2] + wk6[3] + wk6[4] + wk6[5] + 1e-20f;
            #pragma unroll
            for (int k = 0; k < 6; ++k) {
                topk_i[t * 6 + k] = ik[k];
                topk_w[t * 6 + k] = wk6[k] / den;
                atomicAdd(&histL[ik[k]], 1);
            }
        }
    }
    __syncthreads();
    if (tid < 64) histPart[tid * 256 + b] = histL[tid];
}

// ---------------------------------------------------------------------------
// Scan (1 block): per-expert scan over gate blocks, bases, worklist.
// Shared 64-token chunks FIRST (slots 0..255, ~2x staging -> LPT), routed
// 128-token chunks after.
// ---------------------------------------------------------------------------
__global__ __launch_bounds__(256) void k_scan(int* Wi, const int* histPart,
        int* boffG, int* wk) {
    __shared__ int hl[16384];
    __shared__ int cntL[64], exclL[64], chxL[65];
    int tid = threadIdx.x, lane = tid & 63, wv = tid >> 6;
    for (int j = tid; j < 16384; j += 256) hl[j] = histPart[j];
    __syncthreads();
    for (int ei = 0; ei < 16; ++ei) {
        int e = wv * 16 + ei;
        int carry = 0;
        for (int r = 0; r < 4; ++r) {
            int v = hl[e * 256 + r * 64 + lane];
            int incl = v;
            #pragma unroll
            for (int off = 1; off < 64; off <<= 1) {
                int ts = __shfl_up(incl, off);
                if (lane >= off) incl += ts;
            }
            hl[e * 256 + r * 64 + lane] = carry + incl - v;
            carry += __shfl(incl, 63);
        }
        if (lane == 0) cntL[e] = carry;
    }
    __syncthreads();
    if (tid == 0) {
        int s = 0, cs = 0;
        for (int e = 0; e < 64; ++e) {
            exclL[e] = s; s += cntL[e];
            chxL[e] = cs; cs += (cntL[e] + 127) >> 7;
        }
        chxL[64] = cs;
        Wi[128] = s;
        Wi[193] = cs + 256;   // nwork
    }
    __syncthreads();
    if (tid < 64) { Wi[tid] = cntL[tid]; Wi[64 + tid] = exclL[tid]; }
    for (int j = tid; j < 16384; j += 256) boffG[j] = hl[j] + exclL[j >> 8];
    wk[tid] = (64 << 16) | tid;       // 256 shared chunks first
    if (tid < 64) {
        int e = tid, nc = (cntL[e] + 127) >> 7, bb = chxL[e];
        for (int c = 0; c < nc; ++c) wk[256 + bb + c] = (e << 16) | c;
    }
}

// ---------------------------------------------------------------------------
// Scatter: LDS counters seeded from boffG; records pos2 for the gather.
// ---------------------------------------------------------------------------
__global__ __launch_bounds__(256) void k_scatter(const int* topk_i, const float* topk_w,
        const int* boffG, int* perm, float* permw, int* pos2) {
    __shared__ int lcur[64];
    int tid = threadIdx.x, b = blockIdx.x;
    if (tid < 64) lcur[tid] = boffG[tid * 256 + b];
    __syncthreads();
    for (int i = tid; i < 384; i += 256) {
        int g = b * 384 + i;
        int e = topk_i[g];
        float w = topk_w[g];
        int p = atomicAdd(&lcur[e], 1);
        perm[p]  = b * 64 + i / 6;
        permw[p] = w;
        pos2[g]  = p;
    }
}

// ---------------------------------------------------------------------------
// Expert MLP v11 (= R12 v9 + routed GEMM2 loop swap): weights staged via
// global_load_lds (pre-swizzled source, linear LDS dest); B/ad fragments are
// conflict-free ds_read_b128. LDS 72KB, 2 blk/CU. Routed: 128-tok chunk,
// wave owns 32 rows, 3 barriers; GEMM2 preloads bfr[2][3] and streams ad.
// Shared: 64-tok x 2 halves (R12-identical).
// ---------------------------------------------------------------------------
template<int FAST>
__global__ __launch_bounds__(256) void k_expert(const ushort_t* x, const ushort_t* wgT,
        const ushort_t* wuT, const ushort_t* wdP, const int* Wi, const int* wk,
        const int* perm, const float* permw, ushort_t* yperm, ushort_t* ysh, float* ybuf) {
    __shared__ __align__(16) char hl[32768];
    __shared__ __align__(16) char bufA[20480];
    __shared__ __align__(16) char bufB[20480];

    if (blockIdx.x >= Wi[193]) return;
    int entry = wk[blockIdx.x];
    int e = entry >> 16, c = entry & 0xffff;
    int tid = threadIdx.x, lid = tid & 63, wv = tid >> 6;
    int kg  = (lid >> 4) * 16;
    int kq8 = (lid >> 4) * 8;

    if (e < 64) {
        // ---------------- routed: 128-token chunk ----------------
        int n = Wi[e], base = Wi[64 + e];
        int nrows = n - c * 128; if (nrows > 128) nrows = 128;

        // stage wg -> bufA, wu -> bufB (pre-swizzled source, linear dest)
        {
            const ushort_t* gS = wgT + e * 10240;
            const ushort_t* uS = wuT + e * 10240;
            #pragma unroll
            for (int i = 0; i < 5; ++i) {
                int s = wv * 320 + i * 64 + lid;
                int row = s >> 4, sc = (s & 15) ^ (row & 7);
                gl16(bufA + wv * 5120 + i * 1024, gS + row * 128 + sc * 8);
                gl16(bufB + wv * 5120 + i * 1024, uS + row * 128 + sc * 8);
            }
        }
        // A fragments (token gather) into registers
        bf16x8 a[2][4];
        #pragma unroll
        for (int tr = 0; tr < 2; ++tr) {
            int arow = wv * 32 + tr * 16 + (lid & 15);
            int r = (arow < nrows) ? arow : (nrows - 1);
            int t = perm[base + c * 128 + r];
            #pragma unroll
            for (int k = 0; k < 4; ++k)
                a[tr][k] = *(const bf16x8*)(x + t * 128 + k * 32 + kq8);
        }
        __syncthreads();

        // GEMM1: B from LDS
        #pragma unroll
        for (int mi = 0; mi < 5; ++mi) {
            int brow = mi * 16 + (lid & 15);
            int bro = brow * 256, bsw = (brow & 7) << 4;
            f32x4 ag[2], au[2];
            #pragma unroll
            for (int tr = 0; tr < 2; ++tr) {
                ag[tr] = (f32x4){0.f, 0.f, 0.f, 0.f};
                au[tr] = (f32x4){0.f, 0.f, 0.f, 0.f};
            }
            #pragma unroll
            for (int k = 0; k < 4; ++k) {
                int bo = bro + (((k * 64) + kg) ^ bsw);
                bf16x8 bg = *(const bf16x8*)(bufA + bo);
                bf16x8 bu = *(const bf16x8*)(bufB + bo);
                #pragma unroll
                for (int tr = 0; tr < 2; ++tr) {
                    ag[tr] = __builtin_amdgcn_mfma_f32_16x16x32_bf16(a[tr][k], bg, ag[tr], 0, 0, 0);
                    au[tr] = __builtin_amdgcn_mfma_f32_16x16x32_bf16(a[tr][k], bu, au[tr], 0, 0, 0);
                }
            }
            #pragma unroll
            for (int tr = 0; tr < 2; ++tr) {
                #pragma unroll
                for (int rg = 0; rg < 4; ++rg) {
                    float g = ag[tr][rg], uu2 = au[tr][rg];
                    float h = (g / (1.f + __expf(-g))) * uu2;
                    int row = wv * 32 + tr * 16 + (lid >> 4) * 4 + rg;
                    int cb = (mi * 16 + (lid & 15)) * 2;
                    *(ushort_t*)(hl + row * 256 + (cb ^ ((row & 7) << 4))) = f2bf(h);
                }
            }
        }
        {   // zero-pad own rows, K cols 80..95
            int r = wv * 32 + (lid >> 1), ch = 10 + (lid & 1);
            uint4 z = {0u, 0u, 0u, 0u};
            *(uint4*)(hl + r * 256 + ((ch * 16) ^ ((r & 7) << 4))) = z;
        }
        __syncthreads();   // all waves done reading bufA/bufB

        // stage wd rows 0..63 -> bufA, rows 64..127 -> bufB
        {
            const ushort_t* dS = wdP + e * 12288;
            #pragma unroll
            for (int i = 0; i < 4; ++i) {
                int s = wv * 256 + i * 64 + lid;
                int r = s >> 4, sc = (s & 15) ^ (r & 7);
                int off = (sc < 12) ? sc * 8 : 0;
                gl16(bufA + wv * 4096 + i * 1024, dS + r * 96 + off);
                gl16(bufB + wv * 4096 + i * 1024, dS + (64 + r) * 96 + off);
            }
        }
        __syncthreads();

        // GEMM2: preload b-frags (own hl rows, 6 reads), stream ad (3/dt)
        bf16x8 bfr[2][3];
        #pragma unroll
        for (int tf = 0; tf < 2; ++tf) {
            int brow = wv * 32 + tf * 16 + (lid & 15);
            #pragma unroll
            for (int k = 0; k < 3; ++k)
                bfr[tf][k] = *(const bf16x8*)(hl + brow * 256 + (((k * 64) + kg) ^ ((brow & 7) << 4)));
        }
        f32x4 acc[8][2];
        #pragma unroll
        for (int dt = 0; dt < 8; ++dt) {
            acc[dt][0] = (f32x4){0.f, 0.f, 0.f, 0.f};
            acc[dt][1] = (f32x4){0.f, 0.f, 0.f, 0.f};
        }
        #pragma unroll
        for (int dt = 0; dt < 8; ++dt) {
            int r = (dt & 3) * 16 + (lid & 15);
            const char* wb = (dt < 4) ? bufA : bufB;
            bf16x8 ad[3];
            #pragma unroll
            for (int k = 0; k < 3; ++k)
                ad[k] = *(const bf16x8*)(wb + r * 256 + (((k * 64) + kg) ^ ((r & 7) << 4)));
            #pragma unroll
            for (int tf = 0; tf < 2; ++tf) {
                f32x4 cc = acc[dt][tf];
                #pragma unroll
                for (int k = 0; k < 3; ++k)
                    cc = __builtin_amdgcn_mfma_f32_16x16x32_bf16(ad[k], bfr[tf][k], cc, 0, 0, 0);
                acc[dt][tf] = cc;
            }
        }

        // epilogue: scale -> swizzled LDS stage (own rows) -> coalesced stores
        #pragma unroll
        for (int tf = 0; tf < 2; ++tf) {
            int rloc = wv * 32 + tf * 16 + (lid & 15);
            int rc = (rloc < nrows) ? rloc : (nrows - 1);
            float w = FAST ? permw[base + c * 128 + rc] : 0.f;
            #pragma unroll
            for (int dt = 0; dt < 8; ++dt) {
                if (FAST) {
                    int cb = (dt * 16 + (lid >> 4) * 4) * 2;
                    ushort_t o[4];
                    #pragma unroll
                    for (int rg = 0; rg < 4; ++rg) o[rg] = f2bf(acc[dt][tf][rg] * w);
                    *(uint2*)(hl + rloc * 256 + (cb ^ ((rloc & 7) << 4))) = *(const uint2*)o;
                } else {
                    if (rloc < nrows) {
                        int t = perm[base + c * 128 + rloc];
                        float w2 = permw[base + c * 128 + rloc];
                        int d0 = dt * 16 + (lid >> 4) * 4;
                        #pragma unroll
                        for (int rg = 0; rg < 4; ++rg)
                            atomicAdd(&ybuf[t * 128 + d0 + rg], acc[dt][tf][rg] * w2);
                    }
                }
            }
        }
        if (FAST) {
            #pragma unroll
            for (int ps = 0; ps < 8; ++ps) {
                int row = wv * 32 + ps * 4 + (lid >> 4);
                int cb = (lid & 15) * 16;
                uint4 v = *(const uint4*)(hl + row * 256 + (cb ^ ((row & 7) << 4)));
                if (row < nrows)
                    *(uint4*)(yperm + (size_t)(base + c * 128 + row) * 128 + (lid & 15) * 8) = v;
            }
        }
    } else {
        // ---------------- shared: 64-token chunk, 2 halves (R12-identical) --
        bf16x8 a1[4];
        int arow = wv * 16 + (lid & 15);
        int t0 = c * 64 + arow;
        #pragma unroll
        for (int k = 0; k < 4; ++k)
            a1[k] = *(const bf16x8*)(x + t0 * 128 + k * 32 + kq8);

        f32x4 acc[8];
        #pragma unroll
        for (int dt = 0; dt < 8; ++dt) acc[dt] = (f32x4){0.f, 0.f, 0.f, 0.f};

        for (int sub = 0; sub < 2; ++sub) {
            int ee = 64 + sub;
            {
                const ushort_t* gS = wgT + ee * 10240;
                const ushort_t* uS = wuT + ee * 10240;
                #pragma unroll
                for (int i = 0; i < 5; ++i) {
                    int s = wv * 320 + i * 64 + lid;
                    int row = s >> 4, sc = (s & 15) ^ (row & 7);
                    gl16(bufA + wv * 5120 + i * 1024, gS + row * 128 + sc * 8);
                    gl16(bufB + wv * 5120 + i * 1024, uS + row * 128 + sc * 8);
                }
            }
            __syncthreads();
            #pragma unroll
            for (int mi = 0; mi < 5; ++mi) {
                int brow = mi * 16 + (lid & 15);
                int bro = brow * 256, bsw = (brow & 7) << 4;
                f32x4 ag = {0.f, 0.f, 0.f, 0.f};
                f32x4 au = {0.f, 0.f, 0.f, 0.f};
                #pragma unroll
                for (int k = 0; k < 4; ++k) {
                    int bo = bro + (((k * 64) + kg) ^ bsw);
                    bf16x8 bg = *(const bf16x8*)(bufA + bo);
                    bf16x8 bu = *(const bf16x8*)(bufB + bo);
                    ag = __builtin_amdgcn_mfma_f32_16x16x32_bf16(a1[k], bg, ag, 0, 0, 0);
                    au = __builtin_amdgcn_mfma_f32_16x16x32_bf16(a1[k], bu, au, 0, 0, 0);
                }
                #pragma unroll
                for (int rg = 0; rg < 4; ++rg) {
                    float g = ag[rg], uu2 = au[rg];
                    float h = (g / (1.f + __expf(-g))) * uu2;
                    int row = wv * 16 + (lid >> 4) * 4 + rg;
                    int cb = (mi * 16 + (lid & 15)) * 2;
                    *(ushort_t*)(hl + row * 256 + (cb ^ ((row & 7) << 4))) = f2bf(h);
                }
            }
            if (sub == 0 && lid < 32) {
                int r = wv * 16 + (lid >> 1), ch = 10 + (lid & 1);
                uint4 z = {0u, 0u, 0u, 0u};
                *(uint4*)(hl + r * 256 + ((ch * 16) ^ ((r & 7) << 4))) = z;
            }
            __syncthreads();
            {
                const ushort_t* dS = wdP + ee * 12288;
                #pragma unroll
                for (int i = 0; i < 4; ++i) {
                    int s = wv * 256 + i * 64 + lid;
                    int r = s >> 4, sc = (s & 15) ^ (r & 7);
                    int off = (sc < 12) ? sc * 8 : 0;
                    gl16(bufA + wv * 4096 + i * 1024, dS + r * 96 + off);
                    gl16(bufB + wv * 4096 + i * 1024, dS + (64 + r) * 96 + off);
                }
            }
            __syncthreads();
            int brow = wv * 16 + (lid & 15);
            #pragma unroll
            for (int dt = 0; dt < 8; ++dt) {
                int r = (dt & 3) * 16 + (lid & 15);
                const char* wb = (dt < 4) ? bufA : bufB;
                bf16x8 ad[3];
                #pragma unroll
                for (int k = 0; k < 3; ++k)
                    ad[k] = *(const bf16x8*)(wb + r * 256 + (((k * 64) + kg) ^ ((r & 7) << 4)));
                f32x4 cc = acc[dt];
                #pragma unroll
                for (int k = 0; k < 3; ++k) {
                    bf16x8 b = *(const bf16x8*)(hl + brow * 256 + (((k * 64) + kg) ^ ((brow & 7) << 4)));
                    cc = __builtin_amdgcn_mfma_f32_16x16x32_bf16(ad[k], b, cc, 0, 0, 0);
                }
                acc[dt] = cc;
            }
            __syncthreads();   // before restaging bufA/bufB (sub 1)
        }

        int rloc = wv * 16 + (lid & 15);
        if (FAST) {
            #pragma unroll
            for (int dt = 0; dt < 8; ++dt) {
                int cb = (dt * 16 + (lid >> 4) * 4) * 2;
                ushort_t o[4];
                #pragma unroll
                for (int rg = 0; rg < 4; ++rg) o[rg] = f2bf(acc[dt][rg]);
                *(uint2*)(hl + rloc * 256 + (cb ^ ((rloc & 7) << 4))) = *(const uint2*)o;
            }
            #pragma unroll
            for (int ps = 0; ps < 4; ++ps) {
                int row = wv * 16 + ps * 4 + (lid >> 4);
                int cb = (lid & 15) * 16;
                uint4 v = *(const uint4*)(hl + row * 256 + (cb ^ ((row & 7) << 4)));
                *(uint4*)(ysh + (size_t)(c * 64 + row) * 128 + (lid & 15) * 8) = v;
            }
        } else {
            int t = c * 64 + rloc;
            #pragma unroll
            for (int dt = 0; dt < 8; ++dt) {
                int d0 = dt * 16 + (lid >> 4) * 4;
                #pragma unroll
                for (int rg = 0; rg < 4; ++rg)
                    atomicAdd(&ybuf[t * 128 + d0 + rg], acc[dt][rg]);
            }
        }
    }
}

// ---------------------------------------------------------------------------
// Final gather: out[t] = sum_k yperm[pos2[t*6+k]] + ysh[t].
// ---------------------------------------------------------------------------
__global__ __launch_bounds__(256) void k_final_gather(const ushort_t* yperm,
        const ushort_t* ysh, const int* pos2, void* out, const ushort_t* gwDet) {
    int idx = blockIdx.x * 256 + threadIdx.x;
    int t = idx >> 4, cg = (idx & 15) * 8;
    int f32m = detect_f32m(gwDet);
    float acc[8];
    {
        uint4 v = *(const uint4*)(ysh + (size_t)t * 128 + cg);
        const ushort_t* u = (const ushort_t*)&v;
        #pragma unroll
        for (int j = 0; j < 8; ++j) acc[j] = bf2f(u[j]);
    }
    const int* pp = pos2 + t * 6;
    #pragma unroll
    for (int k = 0; k < 6; ++k) {
        int p = pp[k];
        uint4 v = *(const uint4*)(yperm + (size_t)p * 128 + cg);
        const ushort_t* u = (const ushort_t*)&v;
        #pragma unroll
        for (int j = 0; j < 8; ++j) acc[j] += bf2f(u[j]);
    }
    if (f32m) {
        float4 o0 = {acc[0], acc[1], acc[2], acc[3]};
        float4 o1 = {acc[4], acc[5], acc[6], acc[7]};
        float* op = (float*)out + (size_t)t * 128 + cg;
        *(float4*)op = o0; *(float4*)(op + 4) = o1;
    } else {
        ushort_t o[8];
        #pragma unroll
        for (int j = 0; j < 8; ++j) o[j] = f2bf(acc[j]);
        *(uint4*)((ushort_t*)out + (size_t)t * 128 + cg) = *(const uint4*)o;
    }
}

// fallback: read fp32 ybuf
__global__ __launch_bounds__(256) void k_final_ybuf(const float* ybuf, void* out,
        const ushort_t* gwDet) {
    int i = blockIdx.x * 256 + threadIdx.x;
    int f32m = detect_f32m(gwDet);
    float4 v = ((const float4*)ybuf)[i];
    if (f32m) {
        ((float4*)out)[i] = v;
    } else {
        ushort4 o;
        o.x = f2bf(v.x); o.y = f2bf(v.y); o.z = f2bf(v.z); o.w = f2bf(v.w);
        ((ushort4*)out)[i] = o;
    }
}

// ---------------------------------------------------------------------------
extern "C" void kernel_launch(void* const* d_in, const int* in_sizes, int n_in,
                              void* d_out, int out_size, void* d_ws, size_t ws_size,
                              hipStream_t stream) {
    (void)in_sizes; (void)n_in; (void)out_size;
    const void* x   = d_in[0];
    const void* gw  = d_in[1];
    const void* wg  = d_in[2];
    const void* wu  = d_in[3];
    const void* wd  = d_in[4];
    const void* swg = d_in[5];
    const void* swu = d_in[6];
    const void* swd = d_in[7];

    char* ws = (char*)d_ws;
    int fast = (ws_size >= (size_t)NEED_FAST) ? 1 : 0;

    int*      Wi     = (int*)d_ws;
    int*      topk_i = (int*)(ws + OFF_TOPKI);
    int*      wklist = (int*)(ws + OFF_WORK);
    float*    topk_w = (float*)(ws + OFF_TOPKW);
    int*      perm   = (int*)(ws + OFF_PERM);
    float*    permw  = (float*)(ws + OFF_PERMW);
    int*      pos2   = (int*)(ws + OFF_POS2);

    ushort_t* yperm = (ushort_t*)(ws + OFF_YPERM);
    ushort_t* ysh   = (ushort_t*)(ws + OFF_YSH);
    float*    ybuf  = (float*)(ws + FOFF_YBUF);
    ushort_t* wgT   = (ushort_t*)(ws + (fast ? OFF_WGT  : FOFF_WGT));
    ushort_t* wuT   = (ushort_t*)(ws + (fast ? OFF_WUT  : FOFF_WUT));
    ushort_t* wdP   = (ushort_t*)(ws + (fast ? OFF_WDP  : FOFF_WDP));
    ushort_t* xB    = (ushort_t*)(ws + (fast ? OFF_XB   : FOFF_XB));
    int*      histP = (int*)(ws + (fast ? OFF_HIST : FOFF_HIST));
    int*      boffG = (int*)(ws + (fast ? OFF_BOFF : FOFF_BOFF));

    if (!fast) hipMemsetAsync(ybuf, 0, 16384 * 128 * 4, stream);

    k_pg<<<3 * EALL + 256, 1024, 0, stream>>>(x, gw, wg, wu, wd, swg, swu, swd,
                                              wgT, wuT, wdP, xB, topk_i, topk_w, histP);
    k_scan<<<1, 256, 0, stream>>>(Wi, histP, boffG, wklist);
    k_scatter<<<256, 256, 0, stream>>>(topk_i, topk_w, boffG, perm, permw, pos2);
    if (fast) {
        k_expert<1><<<1088, 256, 0, stream>>>(xB, wgT, wuT, wdP, Wi, wklist, perm, permw, yperm, ysh, ybuf);
        k_final_gather<<<1024, 256, 0, stream>>>(yperm, ysh, pos2, d_out, (const ushort_t*)gw);
    } else {
        k_expert<0><<<1088, 256, 0, stream>>>(xB, wgT, wuT, wdP, Wi, wklist, perm, permw, yperm, ysh, ybuf);
        k_final_ybuf<<<2048, 256, 0, stream>>>(ybuf, d_out, (const ushort_t*)gw);
    }
}

// Round 15
// 92.583 us; speedup vs baseline: 1.1169x; 1.0007x over previous
//
#include <hip/hip_runtime.h>
#include <hip/hip_bf16.h>
#include <math.h>

// ---------------------------------------------------------------------------
// DeepseekMoE: T=16384 tokens, D=128, E=64 experts top-6, M=80, shared MS=160.
// R14 = R12 exact (92.8us: global_load_lds staging, pre-swizzled src, shared
//       64-tok chunks x2 subs first) + GEMM2 loop swap in ROUTED path only
//       (preload bfr[2][3] from own hl rows, stream ad: LDS reads 72->30).
//       R13's unified-path/128-tok-shared experiment reverted (regressed).
// ---------------------------------------------------------------------------

typedef unsigned short ushort_t;
typedef __attribute__((ext_vector_type(8))) short bf16x8;   // 8 bf16 = 4 VGPR
typedef __attribute__((ext_vector_type(4))) float f32x4;

#define EALL  66

// ---- fast-mode workspace byte offsets ----
#define OFF_TOPKI 16384
#define OFF_WORK  409600             // int [1088] worklist
#define OFF_TOPKW 802816
#define OFF_PERM  1196032
#define OFF_PERMW 1589248
#define OFF_POS2  1982464
#define OFF_YPERM 2375680            // bf16 [98304][128] = 25165824
#define OFF_YSH   27541504           // bf16 [16384][128] = 4194304
#define OFF_WGT   31735808           // bf16 [66][80][128] = 1351680
#define OFF_WUT   33087488
#define OFF_WDP   34439168           // bf16 [66][128][96] = 1622016 (zero-padded)
#define OFF_XB    36061184           // bf16 [16384][128] = 4194304
#define OFF_HIST  40255488
#define OFF_BOFF  40321024
#define NEED_FAST 40386560
// ---- fallback (compact) offsets: ybuf replaces yperm/ysh ----
#define FOFF_YBUF 2375680            // float[16384*128] = 8388608
#define FOFF_WGT  10764288
#define FOFF_WUT  12115968
#define FOFF_WDP  13467648
#define FOFF_XB   15089664
#define FOFF_HIST 19283968
#define FOFF_BOFF 19349504
// int ws indices: Wi[0..63]=cnt, Wi[64..127]=excl, Wi[128]=total, Wi[193]=nwork.

__device__ __forceinline__ float bf2f(ushort_t u) {
    unsigned int x = ((unsigned int)u) << 16;
    float f; __builtin_memcpy(&f, &x, 4); return f;
}
__device__ __forceinline__ ushort_t f2bf(float f) {
    unsigned int x; __builtin_memcpy(&x, &f, 4);
    unsigned int r = (x + 0x7fffu + ((x >> 16) & 1u)) >> 16;   // RNE
    return (ushort_t)r;
}
__device__ __forceinline__ float ldin(const void* p, int i, int f32m) {
    return f32m ? ((const float*)p)[i] : bf2f(((const ushort_t*)p)[i]);
}
__device__ __forceinline__ int detect_f32m(const ushort_t* gw) {
    int lane = threadIdx.x & 63;
    int cnt = 0;
    #pragma unroll
    for (int j = 0; j < 4; ++j) {
        ushort_t u = gw[lane * 4 + j];
        if (((u >> 7) & 0xFF) >= 0x7C) cnt++;
    }
    #pragma unroll
    for (int off = 32; off; off >>= 1) cnt += __shfl_xor(cnt, off);
    return (cnt >= 8) ? 1 : 0;
}
// async 16B/lane global -> LDS (dest = uniform base + lane*16)
__device__ __forceinline__ void gl16(void* l, const void* g) {
    __builtin_amdgcn_global_load_lds(
        (const __attribute__((address_space(1))) void*)g,
        (__attribute__((address_space(3))) void*)l, 16, 0, 0);
}

// ---------------------------------------------------------------------------
// Fused prep+gate. Blocks [0, 3*EALL): weight transpose (1024 thr).
// Blocks [3*EALL, 3*EALL+256): gating (16 waves x 4 tokens).
// ---------------------------------------------------------------------------
__global__ __launch_bounds__(1024) void k_pg(const void* x, const void* gw,
        const void* wg, const void* wu, const void* wd,
        const void* swg, const void* swu, const void* swd,
        ushort_t* wgT, ushort_t* wuT, ushort_t* wdP,
        ushort_t* xB, int* topk_i, float* topk_w, int* histPart) {
    __shared__ __align__(16) char smem[41984];
    int tid = threadIdx.x, bid = blockIdx.x;
    int f32m = detect_f32m((const ushort_t*)gw);

    if (bid < 3 * EALL) {
        float* lds = (float*)smem;
        int mat = bid / EALL, e = bid % EALL;
        if (mat < 2) {
            const void* src  = (mat == 0) ? wg  : wu;
            const void* ssrc = (mat == 0) ? swg : swu;
            for (int i = tid; i < 10240; i += 1024) {
                int d = i / 80, m = i % 80;
                float v = (e < 64) ? ldin(src, e * 10240 + i, f32m)
                                   : ldin(ssrc, d * 160 + (e - 64) * 80 + m, f32m);
                lds[d * 81 + m] = v;
            }
            __syncthreads();
            ushort_t* dst = ((mat == 0) ? wgT : wuT) + e * 10240;
            for (int o = tid; o < 10240; o += 1024) {
                int m = o >> 7, d = o & 127;
                dst[o] = f2bf(lds[d * 81 + m]);
            }
        } else {
            for (int i = tid; i < 10240; i += 1024) {
                float v = (e < 64) ? ldin(wd, e * 10240 + i, f32m)
                                   : ldin(swd, (e - 64) * 10240 + i, f32m);
                int m = i >> 7, d = i & 127;
                lds[m * 129 + d] = v;
            }
            __syncthreads();
            ushort_t* dst = wdP + e * 12288;
            for (int o = tid; o < 12288; o += 1024) {
                int d = o / 96, m = o % 96;
                dst[o] = (m < 80) ? f2bf(lds[m * 129 + d]) : (ushort_t)0;
            }
        }
        return;
    }

    // -------- gate --------
    float* gwl  = (float*)smem;                 // 64 x 130 f32
    float (*xl)[128] = (float(*)[128])(smem + 33280);
    int*   histL = (int*)(smem + 41472);
    int b = bid - 3 * EALL;
    for (int i = tid; i < 8192; i += 1024)
        gwl[(i >> 7) * 130 + (i & 127)] = ldin(gw, i, f32m);
    if (tid < 64) histL[tid] = 0;
    __syncthreads();
    int wv = tid >> 6, lane = tid & 63;
    for (int q = 0; q < 4; ++q) {
        int t = b * 64 + wv * 4 + q;
        float xv0, xv1;
        if (f32m) {
            float2 v = ((const float2*)((const float*)x + t * 128))[lane];
            xv0 = v.x; xv1 = v.y;
        } else {
            unsigned int pr = *(const unsigned int*)((const ushort_t*)x + t * 128 + lane * 2);
            xv0 = bf2f((ushort_t)(pr & 0xffffu));
            xv1 = bf2f((ushort_t)(pr >> 16));
        }
        float2 xw; xw.x = xv0; xw.y = xv1;
        *(float2*)&xl[wv][lane * 2] = xw;
        unsigned int packed = (unsigned int)f2bf(xv0) | ((unsigned int)f2bf(xv1) << 16);
        *(unsigned int*)(xB + t * 128 + lane * 2) = packed;
        float acc = 0.f;
        #pragma unroll
        for (int d2 = 0; d2 < 64; ++d2) {
            float2 xv = *(const float2*)&xl[wv][d2 * 2];
            float2 gv = *(const float2*)&gwl[lane * 130 + d2 * 2];
            acc = fmaf(xv.x, gv.x, acc);
            acc = fmaf(xv.y, gv.y, acc);
        }
        float mx = acc;
        #pragma unroll
        for (int off = 32; off; off >>= 1) mx = fmaxf(mx, __shfl_xor(mx, off));
        float p = expf(acc - mx);
        float sm = p;
        #pragma unroll
        for (int off = 32; off; off >>= 1) sm += __shfl_xor(sm, off);
        float sc = p / sm;
        float cur = sc;
        float wk6[6]; int ik[6];
        #pragma unroll
        for (int k = 0; k < 6; ++k) {
            float bv = cur; int bi = lane;
            #pragma unroll
            for (int off = 1; off < 64; off <<= 1) {
                float ov = __shfl_xor(bv, off); int oi = __shfl_xor(bi, off);
                if (ov > bv || (ov == bv && oi < bi)) { bv = ov; bi = oi; }
            }
            wk6[k] = bv; ik[k] = bi;
            if (lane == bi) cur = -INFINITY;
        }
        if (lane == 0) {
            float den = wk6[0] + wk6[1] + wk6[2] + wk6[3] + wk6[4] + wk6[5] + 1e-20f;
            #pragma unroll
            for (int k = 0; k < 6; ++k) {
                topk_i[t * 6 + k] = ik[k];
                topk_w[t * 6 + k] = wk6[k] / den;
                atomicAdd(&histL[ik[k]], 1);
            }
        }
    }
    __syncthreads();
    if (tid < 64) histPart[tid * 256 + b] = histL[tid];
}

// ---------------------------------------------------------------------------
// Scan (1 block): per-expert scan over gate blocks, bases, worklist.
// Shared 64-token chunks FIRST (slots 0..255, ~2x staging -> LPT), routed
// 128-token chunks after.
// ---------------------------------------------------------------------------
__global__ __launch_bounds__(256) void k_scan(int* Wi, const int* histPart,
        int* boffG, int* wk) {
    __shared__ int hl[16384];
    __shared__ int cntL[64], exclL[64], chxL[65];
    int tid = threadIdx.x, lane = tid & 63, wv = tid >> 6;
    for (int j = tid; j < 16384; j += 256) hl[j] = histPart[j];
    __syncthreads();
    for (int ei = 0; ei < 16; ++ei) {
        int e = wv * 16 + ei;
        int carry = 0;
        for (int r = 0; r < 4; ++r) {
            int v = hl[e * 256 + r * 64 + lane];
            int incl = v;
            #pragma unroll
            for (int off = 1; off < 64; off <<= 1) {
                int ts = __shfl_up(incl, off);
                if (lane >= off) incl += ts;
            }
            hl[e * 256 + r * 64 + lane] = carry + incl - v;
            carry += __shfl(incl, 63);
        }
        if (lane == 0) cntL[e] = carry;
    }
    __syncthreads();
    if (tid == 0) {
        int s = 0, cs = 0;
        for (int e = 0; e < 64; ++e) {
            exclL[e] = s; s += cntL[e];
            chxL[e] = cs; cs += (cntL[e] + 127) >> 7;
        }
        chxL[64] = cs;
        Wi[128] = s;
        Wi[193] = cs + 256;   // nwork
    }
    __syncthreads();
    if (tid < 64) { Wi[tid] = cntL[tid]; Wi[64 + tid] = exclL[tid]; }
    for (int j = tid; j < 16384; j += 256) boffG[j] = hl[j] + exclL[j >> 8];
    wk[tid] = (64 << 16) | tid;       // 256 shared chunks first
    if (tid < 64) {
        int e = tid, nc = (cntL[e] + 127) >> 7, bb = chxL[e];
        for (int c = 0; c < nc; ++c) wk[256 + bb + c] = (e << 16) | c;
    }
}

// ---------------------------------------------------------------------------
// Scatter: LDS counters seeded from boffG; records pos2 for the gather.
// ---------------------------------------------------------------------------
__global__ __launch_bounds__(256) void k_scatter(const int* topk_i, const float* topk_w,
        const int* boffG, int* perm, float* permw, int* pos2) {
    __shared__ int lcur[64];
    int tid = threadIdx.x, b = blockIdx.x;
    if (tid < 64) lcur[tid] = boffG[tid * 256 + b];
    __syncthreads();
    for (int i = tid; i < 384; i += 256) {
        int g = b * 384 + i;
        int e = topk_i[g];
        float w = topk_w[g];
        int p = atomicAdd(&lcur[e], 1);
        perm[p]  = b * 64 + i / 6;
        permw[p] = w;
        pos2[g]  = p;
    }
}

// ---------------------------------------------------------------------------
// Expert MLP v11 (= R12 v9 + routed GEMM2 loop swap): weights staged via
// global_load_lds (pre-swizzled source, linear LDS dest); B/ad fragments are
// conflict-free ds_read_b128. LDS 72KB, 2 blk/CU. Routed: 128-tok chunk,
// wave owns 32 rows, 3 barriers; GEMM2 preloads bfr[2][3] and streams ad.
// Shared: 64-tok x 2 halves (R12-identical).
// ---------------------------------------------------------------------------
template<int FAST>
__global__ __launch_bounds__(256) void k_expert(const ushort_t* x, const ushort_t* wgT,
        const ushort_t* wuT, const ushort_t* wdP, const int* Wi, const int* wk,
        const int* perm, const float* permw, ushort_t* yperm, ushort_t* ysh, float* ybuf) {
    __shared__ __align__(16) char hl[32768];
    __shared__ __align__(16) char bufA[20480];
    __shared__ __align__(16) char bufB[20480];

    if (blockIdx.x >= Wi[193]) return;
    int entry = wk[blockIdx.x];
    int e = entry >> 16, c = entry & 0xffff;
    int tid = threadIdx.x, lid = tid & 63, wv = tid >> 6;
    int kg  = (lid >> 4) * 16;
    int kq8 = (lid >> 4) * 8;

    if (e < 64) {
        // ---------------- routed: 128-token chunk ----------------
        int n = Wi[e], base = Wi[64 + e];
        int nrows = n - c * 128; if (nrows > 128) nrows = 128;

        // stage wg -> bufA, wu -> bufB (pre-swizzled source, linear dest)
        {
            const ushort_t* gS = wgT + e * 10240;
            const ushort_t* uS = wuT + e * 10240;
            #pragma unroll
            for (int i = 0; i < 5; ++i) {
                int s = wv * 320 + i * 64 + lid;
                int row = s >> 4, sc = (s & 15) ^ (row & 7);
                gl16(bufA + wv * 5120 + i * 1024, gS + row * 128 + sc * 8);
                gl16(bufB + wv * 5120 + i * 1024, uS + row * 128 + sc * 8);
            }
        }
        // A fragments (token gather) into registers
        bf16x8 a[2][4];
        #pragma unroll
        for (int tr = 0; tr < 2; ++tr) {
            int arow = wv * 32 + tr * 16 + (lid & 15);
            int r = (arow < nrows) ? arow : (nrows - 1);
            int t = perm[base + c * 128 + r];
            #pragma unroll
            for (int k = 0; k < 4; ++k)
                a[tr][k] = *(const bf16x8*)(x + t * 128 + k * 32 + kq8);
        }
        __syncthreads();

        // GEMM1: B from LDS
        #pragma unroll
        for (int mi = 0; mi < 5; ++mi) {
            int brow = mi * 16 + (lid & 15);
            int bro = brow * 256, bsw = (brow & 7) << 4;
            f32x4 ag[2], au[2];
            #pragma unroll
            for (int tr = 0; tr < 2; ++tr) {
                ag[tr] = (f32x4){0.f, 0.f, 0.f, 0.f};
                au[tr] = (f32x4){0.f, 0.f, 0.f, 0.f};
            }
            #pragma unroll
            for (int k = 0; k < 4; ++k) {
                int bo = bro + (((k * 64) + kg) ^ bsw);
                bf16x8 bg = *(const bf16x8*)(bufA + bo);
                bf16x8 bu = *(const bf16x8*)(bufB + bo);
                #pragma unroll
                for (int tr = 0; tr < 2; ++tr) {
                    ag[tr] = __builtin_amdgcn_mfma_f32_16x16x32_bf16(a[tr][k], bg, ag[tr], 0, 0, 0);
                    au[tr] = __builtin_amdgcn_mfma_f32_16x16x32_bf16(a[tr][k], bu, au[tr], 0, 0, 0);
                }
            }
            #pragma unroll
            for (int tr = 0; tr < 2; ++tr) {
                #pragma unroll
                for (int rg = 0; rg < 4; ++rg) {
                    float g = ag[tr][rg], uu2 = au[tr][rg];
                    float h = (g / (1.f + __expf(-g))) * uu2;
                    int row = wv * 32 + tr * 16 + (lid >> 4) * 4 + rg;
                    int cb = (mi * 16 + (lid & 15)) * 2;
                    *(ushort_t*)(hl + row * 256 + (cb ^ ((row & 7) << 4))) = f2bf(h);
                }
            }
        }
        {   // zero-pad own rows, K cols 80..95
            int r = wv * 32 + (lid >> 1), ch = 10 + (lid & 1);
            uint4 z = {0u, 0u, 0u, 0u};
            *(uint4*)(hl + r * 256 + ((ch * 16) ^ ((r & 7) << 4))) = z;
        }
        __syncthreads();   // all waves done reading bufA/bufB

        // stage wd rows 0..63 -> bufA, rows 64..127 -> bufB
        {
            const ushort_t* dS = wdP + e * 12288;
            #pragma unroll
            for (int i = 0; i < 4; ++i) {
                int s = wv * 256 + i * 64 + lid;
                int r = s >> 4, sc = (s & 15) ^ (r & 7);
                int off = (sc < 12) ? sc * 8 : 0;
                gl16(bufA + wv * 4096 + i * 1024, dS + r * 96 + off);
                gl16(bufB + wv * 4096 + i * 1024, dS + (64 + r) * 96 + off);
            }
        }
        __syncthreads();

        // GEMM2: preload b-frags (own hl rows, 6 reads), stream ad (3/dt)
        bf16x8 bfr[2][3];
        #pragma unroll
        for (int tf = 0; tf < 2; ++tf) {
            int brow = wv * 32 + tf * 16 + (lid & 15);
            #pragma unroll
            for (int k = 0; k < 3; ++k)
                bfr[tf][k] = *(const bf16x8*)(hl + brow * 256 + (((k * 64) + kg) ^ ((brow & 7) << 4)));
        }
        f32x4 acc[8][2];
        #pragma unroll
        for (int dt = 0; dt < 8; ++dt) {
            acc[dt][0] = (f32x4){0.f, 0.f, 0.f, 0.f};
            acc[dt][1] = (f32x4){0.f, 0.f, 0.f, 0.f};
        }
        #pragma unroll
        for (int dt = 0; dt < 8; ++dt) {
            int r = (dt & 3) * 16 + (lid & 15);
            const char* wb = (dt < 4) ? bufA : bufB;
            bf16x8 ad[3];
            #pragma unroll
            for (int k = 0; k < 3; ++k)
                ad[k] = *(const bf16x8*)(wb + r * 256 + (((k * 64) + kg) ^ ((r & 7) << 4)));
            #pragma unroll
            for (int tf = 0; tf < 2; ++tf) {
                f32x4 cc = acc[dt][tf];
                #pragma unroll
                for (int k = 0; k < 3; ++k)
                    cc = __builtin_amdgcn_mfma_f32_16x16x32_bf16(ad[k], bfr[tf][k], cc, 0, 0, 0);
                acc[dt][tf] = cc;
            }
        }

        // epilogue: scale -> swizzled LDS stage (own rows) -> coalesced stores
        #pragma unroll
        for (int tf = 0; tf < 2; ++tf) {
            int rloc = wv * 32 + tf * 16 + (lid & 15);
            int rc = (rloc < nrows) ? rloc : (nrows - 1);
            float w = FAST ? permw[base + c * 128 + rc] : 0.f;
            #pragma unroll
            for (int dt = 0; dt < 8; ++dt) {
                if (FAST) {
                    int cb = (dt * 16 + (lid >> 4) * 4) * 2;
                    ushort_t o[4];
                    #pragma unroll
                    for (int rg = 0; rg < 4; ++rg) o[rg] = f2bf(acc[dt][tf][rg] * w);
                    *(uint2*)(hl + rloc * 256 + (cb ^ ((rloc & 7) << 4))) = *(const uint2*)o;
                } else {
                    if (rloc < nrows) {
                        int t = perm[base + c * 128 + rloc];
                        float w2 = permw[base + c * 128 + rloc];
                        int d0 = dt * 16 + (lid >> 4) * 4;
                        #pragma unroll
                        for (int rg = 0; rg < 4; ++rg)
                            atomicAdd(&ybuf[t * 128 + d0 + rg], acc[dt][tf][rg] * w2);
                    }
                }
            }
        }
        if (FAST) {
            #pragma unroll
            for (int ps = 0; ps < 8; ++ps) {
                int row = wv * 32 + ps * 4 + (lid >> 4);
                int cb = (lid & 15) * 16;
                uint4 v = *(const uint4*)(hl + row * 256 + (cb ^ ((row & 7) << 4)));
                if (row < nrows)
                    *(uint4*)(yperm + (size_t)(base + c * 128 + row) * 128 + (lid & 15) * 8) = v;
            }
        }
    } else {
        // ---------------- shared: 64-token chunk, 2 halves (R12-identical) --
        bf16x8 a1[4];
        int arow = wv * 16 + (lid & 15);
        int t0 = c * 64 + arow;
        #pragma unroll
        for (int k = 0; k < 4; ++k)
            a1[k] = *(const bf16x8*)(x + t0 * 128 + k * 32 + kq8);

        f32x4 acc[8];
        #pragma unroll
        for (int dt = 0; dt < 8; ++dt) acc[dt] = (f32x4){0.f, 0.f, 0.f, 0.f};

        for (int sub = 0; sub < 2; ++sub) {
            int ee = 64 + sub;
            {
                const ushort_t* gS = wgT + ee * 10240;
                const ushort_t* uS = wuT + ee * 10240;
                #pragma unroll
                for (int i = 0; i < 5; ++i) {
                    int s = wv * 320 + i * 64 + lid;
                    int row = s >> 4, sc = (s & 15) ^ (row & 7);
                    gl16(bufA + wv * 5120 + i * 1024, gS + row * 128 + sc * 8);
                    gl16(bufB + wv * 5120 + i * 1024, uS + row * 128 + sc * 8);
                }
            }
            __syncthreads();
            #pragma unroll
            for (int mi = 0; mi < 5; ++mi) {
                int brow = mi * 16 + (lid & 15);
                int bro = brow * 256, bsw = (brow & 7) << 4;
                f32x4 ag = {0.f, 0.f, 0.f, 0.f};
                f32x4 au = {0.f, 0.f, 0.f, 0.f};
                #pragma unroll
                for (int k = 0; k < 4; ++k) {
                    int bo = bro + (((k * 64) + kg) ^ bsw);
                    bf16x8 bg = *(const bf16x8*)(bufA + bo);
                    bf16x8 bu = *(const bf16x8*)(bufB + bo);
                    ag = __builtin_amdgcn_mfma_f32_16x16x32_bf16(a1[k], bg, ag, 0, 0, 0);
                    au = __builtin_amdgcn_mfma_f32_16x16x32_bf16(a1[k], bu, au, 0, 0, 0);
                }
                #pragma unroll
                for (int rg = 0; rg < 4; ++rg) {
                    float g = ag[rg], uu2 = au[rg];
                    float h = (g / (1.f + __expf(-g))) * uu2;
                    int row = wv * 16 + (lid >> 4) * 4 + rg;
                    int cb = (mi * 16 + (lid & 15)) * 2;
                    *(ushort_t*)(hl + row * 256 + (cb ^ ((row & 7) << 4))) = f2bf(h);
                }
            }
            if (sub == 0 && lid < 32) {
                int r = wv * 16 + (lid >> 1), ch = 10 + (lid & 1);
                uint4 z = {0u, 0u, 0u, 0u};
                *(uint4*)(hl + r * 256 + ((ch * 16) ^ ((r & 7) << 4))) = z;
            }
            __syncthreads();
            {
                const ushort_t* dS = wdP + ee * 12288;
                #pragma unroll
                for (int i = 0; i < 4; ++i) {
                    int s = wv * 256 + i * 64 + lid;
                    int r = s >> 4, sc = (s & 15) ^ (r & 7);
                    int off = (sc < 12) ? sc * 8 : 0;
                    gl16(bufA + wv * 4096 + i * 1024, dS + r * 96 + off);
                    gl16(bufB + wv * 4096 + i * 1024, dS + (64 + r) * 96 + off);
                }
            }
            __syncthreads();
            int brow = wv * 16 + (lid & 15);
            #pragma unroll
            for (int dt = 0; dt < 8; ++dt) {
                int r = (dt & 3) * 16 + (lid & 15);
                const char* wb = (dt < 4) ? bufA : bufB;
                bf16x8 ad[3];
                #pragma unroll
                for (int k = 0; k < 3; ++k)
                    ad[k] = *(const bf16x8*)(wb + r * 256 + (((k * 64) + kg) ^ ((r & 7) << 4)));
                f32x4 cc = acc[dt];
                #pragma unroll
                for (int k = 0; k < 3; ++k) {
                    bf16x8 b = *(const bf16x8*)(hl + brow * 256 + (((k * 64) + kg) ^ ((brow & 7) << 4)));
                    cc = __builtin_amdgcn_mfma_f32_16x16x32_bf16(ad[k], b, cc, 0, 0, 0);
                }
                acc[dt] = cc;
            }
            __syncthreads();   // before restaging bufA/bufB (sub 1)
        }

        int rloc = wv * 16 + (lid & 15);
        if (FAST) {
            #pragma unroll
            for (int dt = 0; dt < 8; ++dt) {
                int cb = (dt * 16 + (lid >> 4) * 4) * 2;
                ushort_t o[4];
                #pragma unroll
                for (int rg = 0; rg < 4; ++rg) o[rg] = f2bf(acc[dt][rg]);
                *(uint2*)(hl + rloc * 256 + (cb ^ ((rloc & 7) << 4))) = *(const uint2*)o;
            }
            #pragma unroll
            for (int ps = 0; ps < 4; ++ps) {
                int row = wv * 16 + ps * 4 + (lid >> 4);
                int cb = (lid & 15) * 16;
                uint4 v = *(const uint4*)(hl + row * 256 + (cb ^ ((row & 7) << 4)));
                *(uint4*)(ysh + (size_t)(c * 64 + row) * 128 + (lid & 15) * 8) = v;
            }
        } else {
            int t = c * 64 + rloc;
            #pragma unroll
            for (int dt = 0; dt < 8; ++dt) {
                int d0 = dt * 16 + (lid >> 4) * 4;
                #pragma unroll
                for (int rg = 0; rg < 4; ++rg)
                    atomicAdd(&ybuf[t * 128 + d0 + rg], acc[dt][rg]);
            }
        }
    }
}

// ---------------------------------------------------------------------------
// Final gather: out[t] = sum_k yperm[pos2[t*6+k]] + ysh[t].
// ---------------------------------------------------------------------------
__global__ __launch_bounds__(256) void k_final_gather(const ushort_t* yperm,
        const ushort_t* ysh, const int* pos2, void* out, const ushort_t* gwDet) {
    int idx = blockIdx.x * 256 + threadIdx.x;
    int t = idx >> 4, cg = (idx & 15) * 8;
    int f32m = detect_f32m(gwDet);
    float acc[8];
    {
        uint4 v = *(const uint4*)(ysh + (size_t)t * 128 + cg);
        const ushort_t* u = (const ushort_t*)&v;
        #pragma unroll
        for (int j = 0; j < 8; ++j) acc[j] = bf2f(u[j]);
    }
    const int* pp = pos2 + t * 6;
    #pragma unroll
    for (int k = 0; k < 6; ++k) {
        int p = pp[k];
        uint4 v = *(const uint4*)(yperm + (size_t)p * 128 + cg);
        const ushort_t* u = (const ushort_t*)&v;
        #pragma unroll
        for (int j = 0; j < 8; ++j) acc[j] += bf2f(u[j]);
    }
    if (f32m) {
        float4 o0 = {acc[0], acc[1], acc[2], acc[3]};
        float4 o1 = {acc[4], acc[5], acc[6], acc[7]};
        float* op = (float*)out + (size_t)t * 128 + cg;
        *(float4*)op = o0; *(float4*)(op + 4) = o1;
    } else {
        ushort_t o[8];
        #pragma unroll
        for (int j = 0; j < 8; ++j) o[j] = f2bf(acc[j]);
        *(uint4*)((ushort_t*)out + (size_t)t * 128 + cg) = *(const uint4*)o;
    }
}

// fallback: read fp32 ybuf
__global__ __launch_bounds__(256) void k_final_ybuf(const float* ybuf, void* out,
        const ushort_t* gwDet) {
    int i = blockIdx.x * 256 + threadIdx.x;
    int f32m = detect_f32m(gwDet);
    float4 v = ((const float4*)ybuf)[i];
    if (f32m) {
        ((float4*)out)[i] = v;
    } else {
        ushort4 o;
        o.x = f2bf(v.x); o.y = f2bf(v.y); o.z = f2bf(v.z); o.w = f2bf(v.w);
        ((ushort4*)out)[i] = o;
    }
}

// ---------------------------------------------------------------------------
extern "C" void kernel_launch(void* const* d_in, const int* in_sizes, int n_in,
                              void* d_out, int out_size, void* d_ws, size_t ws_size,
                              hipStream_t stream) {
    (void)in_sizes; (void)n_in; (void)out_size;
    const void* x   = d_in[0];
    const void* gw  = d_in[1];
    const void* wg  = d_in[2];
    const void* wu  = d_in[3];
    const void* wd  = d_in[4];
    const void* swg = d_in[5];
    const void* swu = d_in[6];
    const void* swd = d_in[7];

    char* ws = (char*)d_ws;
    int fast = (ws_size >= (size_t)NEED_FAST) ? 1 : 0;

    int*      Wi     = (int*)d_ws;
    int*      topk_i = (int*)(ws + OFF_TOPKI);
    int*      wklist = (int*)(ws + OFF_WORK);
    float*    topk_w = (float*)(ws + OFF_TOPKW);
    int*      perm   = (int*)(ws + OFF_PERM);
    float*    permw  = (float*)(ws + OFF_PERMW);
    int*      pos2   = (int*)(ws + OFF_POS2);

    ushort_t* yperm = (ushort_t*)(ws + OFF_YPERM);
    ushort_t* ysh   = (ushort_t*)(ws + OFF_YSH);
    float*    ybuf  = (float*)(ws + FOFF_YBUF);
    ushort_t* wgT   = (ushort_t*)(ws + (fast ? OFF_WGT  : FOFF_WGT));
    ushort_t* wuT   = (ushort_t*)(ws + (fast ? OFF_WUT  : FOFF_WUT));
    ushort_t* wdP   = (ushort_t*)(ws + (fast ? OFF_WDP  : FOFF_WDP));
    ushort_t* xB    = (ushort_t*)(ws + (fast ? OFF_XB   : FOFF_XB));
    int*      histP = (int*)(ws + (fast ? OFF_HIST : FOFF_HIST));
    int*      boffG = (int*)(ws + (fast ? OFF_BOFF : FOFF_BOFF));

    if (!fast) hipMemsetAsync(ybuf, 0, 16384 * 128 * 4, stream);

    k_pg<<<3 * EALL + 256, 1024, 0, stream>>>(x, gw, wg, wu, wd, swg, swu, swd,
                                              wgT, wuT, wdP, xB, topk_i, topk_w, histP);
    k_scan<<<1, 256, 0, stream>>>(Wi, histP, boffG, wklist);
    k_scatter<<<256, 256, 0, stream>>>(topk_i, topk_w, boffG, perm, permw, pos2);
    if (fast) {
        k_expert<1><<<1088, 256, 0, stream>>>(xB, wgT, wuT, wdP, Wi, wklist, perm, permw, yperm, ysh, ybuf);
        k_final_gather<<<1024, 256, 0, stream>>>(yperm, ysh, pos2, d_out, (const ushort_t*)gw);
    } else {
        k_expert<0><<<1088, 256, 0, stream>>>(xB, wgT, wuT, wdP, Wi, wklist, perm, permw, yperm, ysh, ybuf);
        k_final_ybuf<<<2048, 256, 0, stream>>>(ybuf, d_out, (const ushort_t*)gw);
    }
}